// Round 2
// baseline (461.019 us; speedup 1.0000x reference)
//
#include <hip/hip_runtime.h>
#include <hip/hip_bf16.h>

// GraphAttentionLayer: B=8,N=1024,FIN=E=OUT=128,NH=8,HD=16. f32 in/out.
// R27: single persistent kernel (512 blocks x 256 thr), REGULAR launch +
// hand-rolled device-scope grid barrier (R26's hipLaunchCooperativeKernel
// was silently rejected -> out stayed zero; absmax 1.5e-2 == max|ref|).
// Co-residency proof: __launch_bounds__(256,2) caps VGPR<=256, LDS
// 19.2KB/block -> capacity >= 2 blk/CU = 512 >= grid 512, all blocks
// resident at t=0 -> no deadlock. Barrier: atomicAdd + acquire spin +
// __threadfence both sides (G16 cross-XCD discipline). Counters zeroed
// by hipMemsetAsync on stream (capture-safe, replay-idempotent).
// Phase bodies byte-identical to R26 (= ports of passing R25).

using u16 = unsigned short;
typedef short bf16x8 __attribute__((ext_vector_type(8)));
typedef float f32x4 __attribute__((ext_vector_type(4)));
typedef _Float16 f16;
typedef _Float16 f16x4 __attribute__((ext_vector_type(4)));

#define MFMA16(a, b, c) __builtin_amdgcn_mfma_f32_16x16x16f16(a, b, c, 0, 0, 0)
#define MFMAB(a, b, c) __builtin_amdgcn_mfma_f32_16x16x32_bf16(a, b, c, 0, 0, 0)

__device__ __forceinline__ u16 f2b(float f) {
    unsigned u = __float_as_uint(f);
    return (u16)((u + 0x7fffu + ((u >> 16) & 1u)) >> 16);  // RNE
}
__device__ __forceinline__ float b2f(u16 u) {
    return __uint_as_float(((unsigned)u) << 16);
}

// device-scope grid barrier: one counter per phase boundary (no reuse, so
// no sense-reversal needed). All 512 blocks guaranteed resident (see top).
__device__ __forceinline__ void gbar(unsigned* __restrict__ c, unsigned nb) {
    __syncthreads();
    if (threadIdx.x == 0) {
        __threadfence();  // release: drain this block's stores to device scope
        __hip_atomic_fetch_add(c, 1u, __ATOMIC_RELEASE, __HIP_MEMORY_SCOPE_AGENT);
        while (__hip_atomic_load(c, __ATOMIC_ACQUIRE, __HIP_MEMORY_SCOPE_AGENT) < nb)
            __builtin_amdgcn_s_sleep(2);
        __threadfence();  // acquire: invalidate this CU's caches
    }
    __syncthreads();
}

__global__ __launch_bounds__(256, 2)
void gat_mega(const float* __restrict__ H, const float* __restrict__ Aadj,
              const float* __restrict__ Wlin, const float* __restrict__ blin,
              const float* __restrict__ Win, const float* __restrict__ bin,
              const float* __restrict__ Wout, const float* __restrict__ bout,
              const float* __restrict__ Wfin, const float* __restrict__ bfin,
              u16* __restrict__ WinTb, u16* __restrict__ WcombTb,
              float* __restrict__ bcomb, float* __restrict__ rowsum,
              u16* __restrict__ Hpb, f16* __restrict__ qkv,
              u16* __restrict__ ez, u16* __restrict__ ob,
              float* __restrict__ out, unsigned* __restrict__ bars) {
    __shared__ u16 Ks[64 * 40];    // flash: [key][dim of head pair]
    __shared__ u16 VTs[32 * 76];   // flash: [dim][key], bank-safe stride
    __shared__ u16 AWs[64 * 72];   // flash: [qrow][key] bf16 ez

    const int blk = blockIdx.x;    // 0..511
    const int t = threadIdx.x;
    const int wave = t >> 6, lane = t & 63;
    const int wm = (wave >> 1) * 64, wn = (wave & 1) * 64;
    const int m16 = lane & 15, kq = lane >> 4;

    // ================= P0: Hp GEMM (blk<64) + weight prep (blk>=64) =======
    if (blk < 64) {
        const int m0 = blk * 128;
        f32x4 acc[4][4] = {};
#pragma unroll
        for (int kc = 0; kc < 4; ++kc) {
            bf16x8 af[4], bf[4];
#pragma unroll
            for (int i = 0; i < 4; ++i) {
                const float* ap = &H[(long long)(m0 + wm + i * 16 + m16) * 128 + kc * 32 + kq * 8];
                float4 u0 = *(const float4*)ap;
                float4 u1 = *(const float4*)(ap + 4);
                bf16x8 a;
                a[0] = (short)f2b(u0.x); a[1] = (short)f2b(u0.y);
                a[2] = (short)f2b(u0.z); a[3] = (short)f2b(u0.w);
                a[4] = (short)f2b(u1.x); a[5] = (short)f2b(u1.y);
                a[6] = (short)f2b(u1.z); a[7] = (short)f2b(u1.w);
                af[i] = a;
            }
#pragma unroll
            for (int j = 0; j < 4; ++j) {
                const int col = wn + j * 16 + m16;
                const int k0 = kc * 32 + kq * 8;
                bf16x8 bb;
#pragma unroll
                for (int e = 0; e < 8; ++e)
                    bb[e] = (short)f2b(Wlin[(long long)(k0 + e) * 128 + col]);
                bf[j] = bb;
            }
#pragma unroll
            for (int i = 0; i < 4; ++i)
#pragma unroll
                for (int j = 0; j < 4; ++j)
                    acc[i][j] = MFMAB(af[i], bf[j], acc[i][j]);
        }
#pragma unroll
        for (int i = 0; i < 4; ++i) {
#pragma unroll
            for (int r = 0; r < 4; ++r) {
                long long row = m0 + wm + i * 16 + kq * 4 + r;
#pragma unroll
                for (int j = 0; j < 4; ++j) {
                    int col = wn + j * 16 + m16;
                    Hpb[row * 128 + col] = f2b(acc[i][j][r] + blin[col]);
                }
            }
        }
    } else {
        int i = (blk - 64) * 256 + t;        // 0..114687, tasks use 0..73727
        if (i < 8192) {
            rowsum[i] = 0.f;
        } else if (i < 57344) {              // WinTb: Win 128x384 -> 384x128 bf16
            int k = i - 8192;
            int r = k / 384, c = k - r * 384;
            WinTb[c * 128 + r] = f2b(Win[k]);
        } else if (i < 73728) {              // WcombTb = (Wout@Wfin)^T bf16 + bcomb
            int k = i - 57344;
            int o = k & 127, e = k >> 7;     // o fastest: Wfin coalesced
            float s = 0.f;
            for (int kk = 0; kk < 128; ++kk)
                s = fmaf(Wout[e * 128 + kk], Wfin[kk * 128 + o], s);
            WcombTb[o * 128 + e] = f2b(s);
            if (e == 0) {
                float sb = bfin[o];
                for (int kk = 0; kk < 128; ++kk)
                    sb = fmaf(bout[kk], Wfin[kk * 128 + o], sb);
                bcomb[o] = sb;
            }
        }
    }
    gbar(&bars[0], 512);

    // ================= P1: ez tiles (512) + qkv tiles (192) ================
    for (int unit = blk; unit < 704; unit += 512) {
        if (unit < 512) {
            // ez = bf16(exp(lrelu(Hpb@Hpb^T) gated by Aadj!=0)) + exp-rowsum
            const int b = unit >> 6, mt = (unit >> 3) & 7, nt = unit & 7;
            const u16* Ab = Hpb + (long long)b * 1024 * 128;
            const int m0 = mt * 128, n0 = nt * 128;
            f32x4 acc[4][4] = {};
#pragma unroll
            for (int kc = 0; kc < 4; ++kc) {
                bf16x8 af[4], bf[4];
#pragma unroll
                for (int i = 0; i < 4; ++i)
                    af[i] = *(const bf16x8*)&Ab[(long long)(m0 + wm + i * 16 + m16) * 128 + kc * 32 + kq * 8];
#pragma unroll
                for (int j = 0; j < 4; ++j)
                    bf[j] = *(const bf16x8*)&Ab[(long long)(n0 + wn + j * 16 + m16) * 128 + kc * 32 + kq * 8];
#pragma unroll
                for (int i = 0; i < 4; ++i)
#pragma unroll
                    for (int j = 0; j < 4; ++j)
                        acc[i][j] = MFMAB(af[i], bf[j], acc[i][j]);
            }
            const long long zb = (long long)b * 1024 * 1024;
#pragma unroll
            for (int i = 0; i < 4; ++i) {
#pragma unroll
                for (int r = 0; r < 4; ++r) {
                    int row = m0 + wm + i * 16 + kq * 4 + r;
                    float es = 0.f;
#pragma unroll
                    for (int j = 0; j < 4; ++j) {
                        int col = n0 + wn + j * 16 + m16;
                        float v = acc[i][j][r];
                        v = v >= 0.f ? v : 0.2f * v;                    // LeakyReLU(0.2)
                        if (Aadj[zb + (long long)row * 1024 + col] == 0.f) v = 0.f;  // gate
                        float ev = __expf(v);                           // m=0: |z| bounded
                        ez[zb + (long long)row * 1024 + col] = f2b(ev);
                        es += ev;
                    }
#pragma unroll
                    for (int off = 1; off < 16; off <<= 1) es += __shfl_xor(es, off);
                    if (m16 == 0) atomicAdd(&rowsum[b * 1024 + row], es);
                }
            }
        } else {
            // qkv: all f16 (q*0.25 | k | v), 384 halves/row
            const int q = unit - 512;
            const int mt = q & 63, slab = q >> 6;   // 0=q, 1=k, 2=v
            const int m0 = mt * 128;
            const u16* Bslab = WinTb + (long long)slab * 128 * 128;
            f32x4 acc[4][4] = {};
#pragma unroll
            for (int kc = 0; kc < 4; ++kc) {
                bf16x8 af[4], bf[4];
#pragma unroll
                for (int i = 0; i < 4; ++i)
                    af[i] = *(const bf16x8*)&Hpb[(long long)(m0 + wm + i * 16 + m16) * 128 + kc * 32 + kq * 8];
#pragma unroll
                for (int j = 0; j < 4; ++j)
                    bf[j] = *(const bf16x8*)&Bslab[(long long)(wn + j * 16 + m16) * 128 + kc * 32 + kq * 8];
#pragma unroll
                for (int i = 0; i < 4; ++i)
#pragma unroll
                    for (int j = 0; j < 4; ++j)
                        acc[i][j] = MFMAB(af[i], bf[j], acc[i][j]);
            }
            const float qscale = (slab == 0) ? 0.25f : 1.f;  // fold 1/sqrt(HD) into q
#pragma unroll
            for (int i = 0; i < 4; ++i) {
#pragma unroll
                for (int r = 0; r < 4; ++r) {
                    long long row = m0 + wm + i * 16 + kq * 4 + r;
#pragma unroll
                    for (int j = 0; j < 4; ++j) {
                        int col = wn + j * 16 + m16;
                        float v = (acc[i][j][r] + bin[slab * 128 + col]) * qscale;
                        qkv[row * 384 + slab * 128 + col] = (f16)v;
                    }
                }
            }
        }
    }
    gbar(&bars[1], 512);

    // ================= P2: flash (512 blocks: 16 qblk x 8 batch x 4 hpair) =
    {
        const int n0 = (blk & 15) * 64;
        const int b = (blk >> 4) & 7;
        const int h0 = (blk >> 7) * 2;       // 2 heads per block
        const int qr16 = m16, quad = kq, w = wave;

        const int qrow_l = w * 16 + qr16;                 // block-local qrow
        const long long qrow_g = b * 1024 + n0 + qrow_l;  // global qrow
        const float inv0 = 1.f / rowsum[qrow_g];

        f16x4 qf[2];
#pragma unroll
        for (int hh = 0; hh < 2; ++hh)
            qf[hh] = *(const f16x4*)&qkv[qrow_g * 384 + (h0 + hh) * 16 + quad * 4];

        f32x4 accO[2] = {};
        float lacc[2] = {0.f, 0.f};

        for (int st = 0; st < 16; ++st) {
            const int kb = st * 64;
            __syncthreads();
            // stage K (64 keys x 32 dims) b128: key = t>>2, c8 = t&3
            {
                const int key = t >> 2, c8 = t & 3;
                *(uint4*)&Ks[key * 40 + c8 * 8] =
                    *(const uint4*)&qkv[((long long)(b * 1024 + kb + key)) * 384 + 128 + h0 * 16 + c8 * 8];
                // stage V transposed: VTs[dim][key]; bank-step 16 -> <=2-way
                const f16* vsrc = &qkv[((long long)(b * 1024 + kb + key)) * 384 + 256 + h0 * 16 + c8 * 8];
                f16x4 v0 = *(const f16x4*)vsrc;
                f16x4 v1 = *(const f16x4*)(vsrc + 4);
                const int d0 = c8 * 8;
#pragma unroll
                for (int i = 0; i < 4; ++i) {
                    VTs[(d0 + i) * 76 + key] = ((const u16*)&v0)[i];
                    VTs[(d0 + 4 + i) * 76 + key] = ((const u16*)&v1)[i];
                }
            }
            // stage AW (64 qrows x 64 keys) b128
#pragma unroll
            for (int rr = 0; rr < 2; ++rr) {
                int idx = rr * 256 + t;
                int row = idx >> 3, c16 = idx & 7;
                *(uint4*)&AWs[row * 72 + c16 * 8] =
                    *(const uint4*)&ez[((long long)(b * 1024 + n0 + row)) * 1024 + kb + c16 * 8];
            }
            __syncthreads();

#pragma unroll 2
            for (int kt = 0; kt < 4; ++kt) {
                // aw C-init: lane holds (qrow=qr16, keys kt*16+quad*4+r)
                ushort4 ue = *(const ushort4*)&AWs[qrow_l * 72 + kt * 16 + quad * 4];
                f32x4 aw0;
                aw0[0] = b2f(ue.x) * inv0; aw0[1] = b2f(ue.y) * inv0;
                aw0[2] = b2f(ue.z) * inv0; aw0[3] = b2f(ue.w) * inv0;
#pragma unroll
                for (int hh = 0; hh < 2; ++hh) {
                    f16x4 kf = *(const f16x4*)&Ks[(kt * 16 + qr16) * 40 + hh * 16 + quad * 4];
                    f32x4 s4 = MFMA16(kf, qf[hh], aw0);
                    float p0 = __expf(s4[0]), p1 = __expf(s4[1]);
                    float p2 = __expf(s4[2]), p3 = __expf(s4[3]);
                    lacc[hh] += (p0 + p1) + (p2 + p3);
                    f16x4 pf;
                    pf[0] = (f16)p0; pf[1] = (f16)p1; pf[2] = (f16)p2; pf[3] = (f16)p3;
                    f16x4 vf = *(const f16x4*)&VTs[(hh * 16 + qr16) * 76 + kt * 16 + quad * 4];
                    accO[hh] = MFMA16(vf, pf, accO[hh]);
                }
            }
        }
        // finalize: l over quads, store o normalized as bf16 (same rounding
        // as R25's mfma_out A-pack)
#pragma unroll
        for (int hh = 0; hh < 2; ++hh) {
            float l = lacc[hh];
            l += __shfl_xor(l, 16);
            l += __shfl_xor(l, 32);
            float inv = 1.f / l;
            ushort4 st4;
            st4.x = f2b(accO[hh][0] * inv);
            st4.y = f2b(accO[hh][1] * inv);
            st4.z = f2b(accO[hh][2] * inv);
            st4.w = f2b(accO[hh][3] * inv);
            *(ushort4*)&ob[qrow_g * 128 + (h0 + hh) * 16 + quad * 4] = st4;
        }
    }
    gbar(&bars[2], 512);

    // ================= P3: out = ob @ WcombTb^T + bcomb (blk<64) ===========
    if (blk < 64) {
        const int m0 = blk * 128;
        f32x4 acc[4][4] = {};
#pragma unroll
        for (int kc = 0; kc < 4; ++kc) {
            bf16x8 af[4], bf[4];
#pragma unroll
            for (int i = 0; i < 4; ++i)
                af[i] = *(const bf16x8*)&ob[(long long)(m0 + wm + i * 16 + m16) * 128 + kc * 32 + kq * 8];
#pragma unroll
            for (int j = 0; j < 4; ++j)
                bf[j] = *(const bf16x8*)&WcombTb[(long long)(wn + j * 16 + m16) * 128 + kc * 32 + kq * 8];
#pragma unroll
            for (int i = 0; i < 4; ++i)
#pragma unroll
                for (int j = 0; j < 4; ++j)
                    acc[i][j] = MFMAB(af[i], bf[j], acc[i][j]);
        }
#pragma unroll
        for (int i = 0; i < 4; ++i) {
#pragma unroll
            for (int r = 0; r < 4; ++r) {
                long long row = m0 + wm + i * 16 + kq * 4 + r;
#pragma unroll
                for (int j = 0; j < 4; ++j) {
                    int col = wn + j * 16 + m16;
                    out[row * 128 + col] = acc[i][j][r] + bcomb[col];
                }
            }
        }
    }
}

extern "C" void kernel_launch(void* const* d_in, const int* in_sizes, int n_in,
                              void* d_out, int out_size, void* d_ws, size_t ws_size,
                              hipStream_t stream) {
    (void)in_sizes; (void)n_in; (void)out_size; (void)ws_size;
    const float* H    = (const float*)d_in[0];
    const float* Aadj = (const float*)d_in[1];
    const float* Wlin = (const float*)d_in[2];
    const float* blin = (const float*)d_in[3];
    const float* Win  = (const float*)d_in[4];
    const float* bin  = (const float*)d_in[5];
    const float* Wout = (const float*)d_in[6];
    const float* bout = (const float*)d_in[7];
    const float* Wfin = (const float*)d_in[8];
    const float* bfin = (const float*)d_in[9];
    float* out = (float*)d_out;
    char* ws = (char*)d_ws;

    u16*   WinTb   = (u16*)(ws + 0);          // 96 KB bf16
    u16*   WcombTb = (u16*)(ws + 98304);      // 32 KB bf16
    float* bcomb   = (float*)(ws + 131072);   // 512 B
    float* rowsum  = (float*)(ws + 131584);   // 32 KB
    u16*   Hpb     = (u16*)(ws + 262144);     // 2 MB bf16
    f16*   qkvp    = (f16*)(ws + 2359296);    // 6 MB (q f16*0.25 | k | v)
    u16*   ob      = (u16*)(ws + 8650752);    // 2 MB bf16 normalized o
    u16*   ez      = (u16*)(ws + 12845056);   // 16 MB bf16 exp(z)
    unsigned* bars = (unsigned*)(ws + 29622272);  // 3 barrier counters

    // zero barrier counters (capture-safe, replay-idempotent)
    hipMemsetAsync(bars, 0, 16, stream);
    gat_mega<<<512, 256, 0, stream>>>(H, Aadj, Wlin, blin, Win, bin, Wout,
                                      bout, Wfin, bfin, WinTb, WcombTb, bcomb,
                                      rowsum, Hpb, qkvp, ez, ob, out, bars);
}

// Round 3
// 307.842 us; speedup vs baseline: 1.4976x; 1.4976x over previous
//
#include <hip/hip_runtime.h>
#include <hip/hip_bf16.h>

// GraphAttentionLayer: B=8,N=1024,FIN=E=OUT=128,NH=8,HD=16. f32 in/out.
// R28: R27 with the grid-barrier spin fixed. R27's spin used ACQUIRE
// agent-scope loads -> buffer_inv (L1+L2 invalidate) EVERY poll from ~500
// waiting blocks -> cache/fabric storm -> 92MB moved at 240GB/s, 387us.
// Fix: RELAXED spin loads (still coherence-point routed, no invalidate),
// ONE __threadfence() after spin exit (single acquire/invalidate), and
// s_sleep(16) poll period. Everything else byte-identical to R27.

using u16 = unsigned short;
typedef short bf16x8 __attribute__((ext_vector_type(8)));
typedef float f32x4 __attribute__((ext_vector_type(4)));
typedef _Float16 f16;
typedef _Float16 f16x4 __attribute__((ext_vector_type(4)));

#define MFMA16(a, b, c) __builtin_amdgcn_mfma_f32_16x16x16f16(a, b, c, 0, 0, 0)
#define MFMAB(a, b, c) __builtin_amdgcn_mfma_f32_16x16x32_bf16(a, b, c, 0, 0, 0)

__device__ __forceinline__ u16 f2b(float f) {
    unsigned u = __float_as_uint(f);
    return (u16)((u + 0x7fffu + ((u >> 16) & 1u)) >> 16);  // RNE
}
__device__ __forceinline__ float b2f(u16 u) {
    return __uint_as_float(((unsigned)u) << 16);
}

// device-scope grid barrier: one counter per phase boundary (no reuse, so
// no sense-reversal needed). All 512 blocks guaranteed resident (see top).
// RELAXED spin (no per-poll cache invalidate); one release fence before
// arrive, one acquire fence after exit (G16 cross-XCD discipline).
__device__ __forceinline__ void gbar(unsigned* __restrict__ c, unsigned nb) {
    __syncthreads();
    if (threadIdx.x == 0) {
        __threadfence();  // release: writeback this block's stores
        __hip_atomic_fetch_add(c, 1u, __ATOMIC_RELAXED, __HIP_MEMORY_SCOPE_AGENT);
        while (__hip_atomic_load(c, __ATOMIC_RELAXED, __HIP_MEMORY_SCOPE_AGENT) < nb)
            __builtin_amdgcn_s_sleep(16);
        __threadfence();  // acquire: invalidate once, after exit
    }
    __syncthreads();
}

__global__ __launch_bounds__(256, 2)
void gat_mega(const float* __restrict__ H, const float* __restrict__ Aadj,
              const float* __restrict__ Wlin, const float* __restrict__ blin,
              const float* __restrict__ Win, const float* __restrict__ bin,
              const float* __restrict__ Wout, const float* __restrict__ bout,
              const float* __restrict__ Wfin, const float* __restrict__ bfin,
              u16* __restrict__ WinTb, u16* __restrict__ WcombTb,
              float* __restrict__ bcomb, float* __restrict__ rowsum,
              u16* __restrict__ Hpb, f16* __restrict__ qkv,
              u16* __restrict__ ez, u16* __restrict__ ob,
              float* __restrict__ out, unsigned* __restrict__ bars) {
    __shared__ u16 Ks[64 * 40];    // flash: [key][dim of head pair]
    __shared__ u16 VTs[32 * 76];   // flash: [dim][key], bank-safe stride
    __shared__ u16 AWs[64 * 72];   // flash: [qrow][key] bf16 ez

    const int blk = blockIdx.x;    // 0..511
    const int t = threadIdx.x;
    const int wave = t >> 6, lane = t & 63;
    const int wm = (wave >> 1) * 64, wn = (wave & 1) * 64;
    const int m16 = lane & 15, kq = lane >> 4;

    // ================= P0: Hp GEMM (blk<64) + weight prep (blk>=64) =======
    if (blk < 64) {
        const int m0 = blk * 128;
        f32x4 acc[4][4] = {};
#pragma unroll
        for (int kc = 0; kc < 4; ++kc) {
            bf16x8 af[4], bf[4];
#pragma unroll
            for (int i = 0; i < 4; ++i) {
                const float* ap = &H[(long long)(m0 + wm + i * 16 + m16) * 128 + kc * 32 + kq * 8];
                float4 u0 = *(const float4*)ap;
                float4 u1 = *(const float4*)(ap + 4);
                bf16x8 a;
                a[0] = (short)f2b(u0.x); a[1] = (short)f2b(u0.y);
                a[2] = (short)f2b(u0.z); a[3] = (short)f2b(u0.w);
                a[4] = (short)f2b(u1.x); a[5] = (short)f2b(u1.y);
                a[6] = (short)f2b(u1.z); a[7] = (short)f2b(u1.w);
                af[i] = a;
            }
#pragma unroll
            for (int j = 0; j < 4; ++j) {
                const int col = wn + j * 16 + m16;
                const int k0 = kc * 32 + kq * 8;
                bf16x8 bb;
#pragma unroll
                for (int e = 0; e < 8; ++e)
                    bb[e] = (short)f2b(Wlin[(long long)(k0 + e) * 128 + col]);
                bf[j] = bb;
            }
#pragma unroll
            for (int i = 0; i < 4; ++i)
#pragma unroll
                for (int j = 0; j < 4; ++j)
                    acc[i][j] = MFMAB(af[i], bf[j], acc[i][j]);
        }
#pragma unroll
        for (int i = 0; i < 4; ++i) {
#pragma unroll
            for (int r = 0; r < 4; ++r) {
                long long row = m0 + wm + i * 16 + kq * 4 + r;
#pragma unroll
                for (int j = 0; j < 4; ++j) {
                    int col = wn + j * 16 + m16;
                    Hpb[row * 128 + col] = f2b(acc[i][j][r] + blin[col]);
                }
            }
        }
    } else {
        int i = (blk - 64) * 256 + t;        // 0..114687, tasks use 0..73727
        if (i < 8192) {
            rowsum[i] = 0.f;
        } else if (i < 57344) {              // WinTb: Win 128x384 -> 384x128 bf16
            int k = i - 8192;
            int r = k / 384, c = k - r * 384;
            WinTb[c * 128 + r] = f2b(Win[k]);
        } else if (i < 73728) {              // WcombTb = (Wout@Wfin)^T bf16 + bcomb
            int k = i - 57344;
            int o = k & 127, e = k >> 7;     // o fastest: Wfin coalesced
            float s = 0.f;
            for (int kk = 0; kk < 128; ++kk)
                s = fmaf(Wout[e * 128 + kk], Wfin[kk * 128 + o], s);
            WcombTb[o * 128 + e] = f2b(s);
            if (e == 0) {
                float sb = bfin[o];
                for (int kk = 0; kk < 128; ++kk)
                    sb = fmaf(bout[kk], Wfin[kk * 128 + o], sb);
                bcomb[o] = sb;
            }
        }
    }
    gbar(&bars[0], 512);

    // ================= P1: ez tiles (512) + qkv tiles (192) ================
    for (int unit = blk; unit < 704; unit += 512) {
        if (unit < 512) {
            // ez = bf16(exp(lrelu(Hpb@Hpb^T) gated by Aadj!=0)) + exp-rowsum
            const int b = unit >> 6, mt = (unit >> 3) & 7, nt = unit & 7;
            const u16* Ab = Hpb + (long long)b * 1024 * 128;
            const int m0 = mt * 128, n0 = nt * 128;
            f32x4 acc[4][4] = {};
#pragma unroll
            for (int kc = 0; kc < 4; ++kc) {
                bf16x8 af[4], bf[4];
#pragma unroll
                for (int i = 0; i < 4; ++i)
                    af[i] = *(const bf16x8*)&Ab[(long long)(m0 + wm + i * 16 + m16) * 128 + kc * 32 + kq * 8];
#pragma unroll
                for (int j = 0; j < 4; ++j)
                    bf[j] = *(const bf16x8*)&Ab[(long long)(n0 + wn + j * 16 + m16) * 128 + kc * 32 + kq * 8];
#pragma unroll
                for (int i = 0; i < 4; ++i)
#pragma unroll
                    for (int j = 0; j < 4; ++j)
                        acc[i][j] = MFMAB(af[i], bf[j], acc[i][j]);
            }
            const long long zb = (long long)b * 1024 * 1024;
#pragma unroll
            for (int i = 0; i < 4; ++i) {
#pragma unroll
                for (int r = 0; r < 4; ++r) {
                    int row = m0 + wm + i * 16 + kq * 4 + r;
                    float es = 0.f;
#pragma unroll
                    for (int j = 0; j < 4; ++j) {
                        int col = n0 + wn + j * 16 + m16;
                        float v = acc[i][j][r];
                        v = v >= 0.f ? v : 0.2f * v;                    // LeakyReLU(0.2)
                        if (Aadj[zb + (long long)row * 1024 + col] == 0.f) v = 0.f;  // gate
                        float ev = __expf(v);                           // m=0: |z| bounded
                        ez[zb + (long long)row * 1024 + col] = f2b(ev);
                        es += ev;
                    }
#pragma unroll
                    for (int off = 1; off < 16; off <<= 1) es += __shfl_xor(es, off);
                    if (m16 == 0) atomicAdd(&rowsum[b * 1024 + row], es);
                }
            }
        } else {
            // qkv: all f16 (q*0.25 | k | v), 384 halves/row
            const int q = unit - 512;
            const int mt = q & 63, slab = q >> 6;   // 0=q, 1=k, 2=v
            const int m0 = mt * 128;
            const u16* Bslab = WinTb + (long long)slab * 128 * 128;
            f32x4 acc[4][4] = {};
#pragma unroll
            for (int kc = 0; kc < 4; ++kc) {
                bf16x8 af[4], bf[4];
#pragma unroll
                for (int i = 0; i < 4; ++i)
                    af[i] = *(const bf16x8*)&Hpb[(long long)(m0 + wm + i * 16 + m16) * 128 + kc * 32 + kq * 8];
#pragma unroll
                for (int j = 0; j < 4; ++j)
                    bf[j] = *(const bf16x8*)&Bslab[(long long)(wn + j * 16 + m16) * 128 + kc * 32 + kq * 8];
#pragma unroll
                for (int i = 0; i < 4; ++i)
#pragma unroll
                    for (int j = 0; j < 4; ++j)
                        acc[i][j] = MFMAB(af[i], bf[j], acc[i][j]);
            }
            const float qscale = (slab == 0) ? 0.25f : 1.f;  // fold 1/sqrt(HD) into q
#pragma unroll
            for (int i = 0; i < 4; ++i) {
#pragma unroll
                for (int r = 0; r < 4; ++r) {
                    long long row = m0 + wm + i * 16 + kq * 4 + r;
#pragma unroll
                    for (int j = 0; j < 4; ++j) {
                        int col = wn + j * 16 + m16;
                        float v = (acc[i][j][r] + bin[slab * 128 + col]) * qscale;
                        qkv[row * 384 + slab * 128 + col] = (f16)v;
                    }
                }
            }
        }
    }
    gbar(&bars[1], 512);

    // ================= P2: flash (512 blocks: 16 qblk x 8 batch x 4 hpair) =
    {
        const int n0 = (blk & 15) * 64;
        const int b = (blk >> 4) & 7;
        const int h0 = (blk >> 7) * 2;       // 2 heads per block
        const int qr16 = m16, quad = kq, w = wave;

        const int qrow_l = w * 16 + qr16;                 // block-local qrow
        const long long qrow_g = b * 1024 + n0 + qrow_l;  // global qrow
        const float inv0 = 1.f / rowsum[qrow_g];

        f16x4 qf[2];
#pragma unroll
        for (int hh = 0; hh < 2; ++hh)
            qf[hh] = *(const f16x4*)&qkv[qrow_g * 384 + (h0 + hh) * 16 + quad * 4];

        f32x4 accO[2] = {};
        float lacc[2] = {0.f, 0.f};

        for (int st = 0; st < 16; ++st) {
            const int kb = st * 64;
            __syncthreads();
            // stage K (64 keys x 32 dims) b128: key = t>>2, c8 = t&3
            {
                const int key = t >> 2, c8 = t & 3;
                *(uint4*)&Ks[key * 40 + c8 * 8] =
                    *(const uint4*)&qkv[((long long)(b * 1024 + kb + key)) * 384 + 128 + h0 * 16 + c8 * 8];
                // stage V transposed: VTs[dim][key]; bank-step 16 -> <=2-way
                const f16* vsrc = &qkv[((long long)(b * 1024 + kb + key)) * 384 + 256 + h0 * 16 + c8 * 8];
                f16x4 v0 = *(const f16x4*)vsrc;
                f16x4 v1 = *(const f16x4*)(vsrc + 4);
                const int d0 = c8 * 8;
#pragma unroll
                for (int i = 0; i < 4; ++i) {
                    VTs[(d0 + i) * 76 + key] = ((const u16*)&v0)[i];
                    VTs[(d0 + 4 + i) * 76 + key] = ((const u16*)&v1)[i];
                }
            }
            // stage AW (64 qrows x 64 keys) b128
#pragma unroll
            for (int rr = 0; rr < 2; ++rr) {
                int idx = rr * 256 + t;
                int row = idx >> 3, c16 = idx & 7;
                *(uint4*)&AWs[row * 72 + c16 * 8] =
                    *(const uint4*)&ez[((long long)(b * 1024 + n0 + row)) * 1024 + kb + c16 * 8];
            }
            __syncthreads();

#pragma unroll 2
            for (int kt = 0; kt < 4; ++kt) {
                // aw C-init: lane holds (qrow=qr16, keys kt*16+quad*4+r)
                ushort4 ue = *(const ushort4*)&AWs[qrow_l * 72 + kt * 16 + quad * 4];
                f32x4 aw0;
                aw0[0] = b2f(ue.x) * inv0; aw0[1] = b2f(ue.y) * inv0;
                aw0[2] = b2f(ue.z) * inv0; aw0[3] = b2f(ue.w) * inv0;
#pragma unroll
                for (int hh = 0; hh < 2; ++hh) {
                    f16x4 kf = *(const f16x4*)&Ks[(kt * 16 + qr16) * 40 + hh * 16 + quad * 4];
                    f32x4 s4 = MFMA16(kf, qf[hh], aw0);
                    float p0 = __expf(s4[0]), p1 = __expf(s4[1]);
                    float p2 = __expf(s4[2]), p3 = __expf(s4[3]);
                    lacc[hh] += (p0 + p1) + (p2 + p3);
                    f16x4 pf;
                    pf[0] = (f16)p0; pf[1] = (f16)p1; pf[2] = (f16)p2; pf[3] = (f16)p3;
                    f16x4 vf = *(const f16x4*)&VTs[(hh * 16 + qr16) * 76 + kt * 16 + quad * 4];
                    accO[hh] = MFMA16(vf, pf, accO[hh]);
                }
            }
        }
        // finalize: l over quads, store o normalized as bf16 (same rounding
        // as R25's mfma_out A-pack)
#pragma unroll
        for (int hh = 0; hh < 2; ++hh) {
            float l = lacc[hh];
            l += __shfl_xor(l, 16);
            l += __shfl_xor(l, 32);
            float inv = 1.f / l;
            ushort4 st4;
            st4.x = f2b(accO[hh][0] * inv);
            st4.y = f2b(accO[hh][1] * inv);
            st4.z = f2b(accO[hh][2] * inv);
            st4.w = f2b(accO[hh][3] * inv);
            *(ushort4*)&ob[qrow_g * 128 + (h0 + hh) * 16 + quad * 4] = st4;
        }
    }
    gbar(&bars[2], 512);

    // ================= P3: out = ob @ WcombTb^T + bcomb (blk<64) ===========
    if (blk < 64) {
        const int m0 = blk * 128;
        f32x4 acc[4][4] = {};
#pragma unroll
        for (int kc = 0; kc < 4; ++kc) {
            bf16x8 af[4], bf[4];
#pragma unroll
            for (int i = 0; i < 4; ++i)
                af[i] = *(const bf16x8*)&ob[(long long)(m0 + wm + i * 16 + m16) * 128 + kc * 32 + kq * 8];
#pragma unroll
            for (int j = 0; j < 4; ++j)
                bf[j] = *(const bf16x8*)&WcombTb[(long long)(wn + j * 16 + m16) * 128 + kc * 32 + kq * 8];
#pragma unroll
            for (int i = 0; i < 4; ++i)
#pragma unroll
                for (int j = 0; j < 4; ++j)
                    acc[i][j] = MFMAB(af[i], bf[j], acc[i][j]);
        }
#pragma unroll
        for (int i = 0; i < 4; ++i) {
#pragma unroll
            for (int r = 0; r < 4; ++r) {
                long long row = m0 + wm + i * 16 + kq * 4 + r;
#pragma unroll
                for (int j = 0; j < 4; ++j) {
                    int col = wn + j * 16 + m16;
                    out[row * 128 + col] = acc[i][j][r] + bcomb[col];
                }
            }
        }
    }
}

extern "C" void kernel_launch(void* const* d_in, const int* in_sizes, int n_in,
                              void* d_out, int out_size, void* d_ws, size_t ws_size,
                              hipStream_t stream) {
    (void)in_sizes; (void)n_in; (void)out_size; (void)ws_size;
    const float* H    = (const float*)d_in[0];
    const float* Aadj = (const float*)d_in[1];
    const float* Wlin = (const float*)d_in[2];
    const float* blin = (const float*)d_in[3];
    const float* Win  = (const float*)d_in[4];
    const float* bin  = (const float*)d_in[5];
    const float* Wout = (const float*)d_in[6];
    const float* bout = (const float*)d_in[7];
    const float* Wfin = (const float*)d_in[8];
    const float* bfin = (const float*)d_in[9];
    float* out = (float*)d_out;
    char* ws = (char*)d_ws;

    u16*   WinTb   = (u16*)(ws + 0);          // 96 KB bf16
    u16*   WcombTb = (u16*)(ws + 98304);      // 32 KB bf16
    float* bcomb   = (float*)(ws + 131072);   // 512 B
    float* rowsum  = (float*)(ws + 131584);   // 32 KB
    u16*   Hpb     = (u16*)(ws + 262144);     // 2 MB bf16
    f16*   qkvp    = (f16*)(ws + 2359296);    // 6 MB (q f16*0.25 | k | v)
    u16*   ob      = (u16*)(ws + 8650752);    // 2 MB bf16 normalized o
    u16*   ez      = (u16*)(ws + 12845056);   // 16 MB bf16 exp(z)
    unsigned* bars = (unsigned*)(ws + 29622272);  // 3 barrier counters

    // zero barrier counters (capture-safe, replay-idempotent)
    hipMemsetAsync(bars, 0, 16, stream);
    gat_mega<<<512, 256, 0, stream>>>(H, Aadj, Wlin, blin, Win, bin, Wout,
                                      bout, Wfin, bfin, WinTb, WcombTb, bcomb,
                                      rowsum, Hpb, qkvp, ez, ob, out, bars);
}

// Round 4
// 173.860 us; speedup vs baseline: 2.6517x; 1.7706x over previous
//
#include <hip/hip_runtime.h>
#include <hip/hip_bf16.h>

// GraphAttentionLayer: B=8,N=1024,FIN=E=OUT=128,NH=8,HD=16. f32 in/out.
// R29: revert to R25's proven 4-dispatch structure (mega-kernel refuted:
// per-block L2 wb/inv fences at software grid barriers cost ~130us, R27/R28
// evidence). Changes vs R25, both pure grid-parallelism (latency-bound tiny
// grids): (1) mfma_out 64->128 blocks (64-row tiles, wave=16rowsx128cols);
// (2) mfma_qkvz ez section 512->1024 tiles (128x64, waves 2x2, j-loop 2).
// prep_hp / flash_mfma byte-identical to R25 (160.8us, absmax 9.2e-5).

using u16 = unsigned short;
typedef short bf16x8 __attribute__((ext_vector_type(8)));
typedef float f32x4 __attribute__((ext_vector_type(4)));
typedef _Float16 f16;
typedef _Float16 f16x4 __attribute__((ext_vector_type(4)));

#define MFMA16(a, b, c) __builtin_amdgcn_mfma_f32_16x16x16f16(a, b, c, 0, 0, 0)
#define MFMAB(a, b, c) __builtin_amdgcn_mfma_f32_16x16x32_bf16(a, b, c, 0, 0, 0)

__device__ __forceinline__ u16 f2b(float f) {
    unsigned u = __float_as_uint(f);
    return (u16)((u + 0x7fffu + ((u >> 16) & 1u)) >> 16);  // RNE
}
__device__ __forceinline__ float b2f(u16 u) {
    return __uint_as_float(((unsigned)u) << 16);
}

// ---- merged prep + Hp-GEMM ----
// blk < 64: Hp = cast(H) @ cast(Wlin)^T + blin  (MFMA, both frags packed
//           in-register from f32; B-frag via strided Wlin reads).
// blk >= 64: rowsum zero + WinTb bf16 + WcombTb bf16 + bcomb + Aadj->u8.
__global__ void prep_hp(const float* __restrict__ H, const float* __restrict__ Wlin,
                        const float* __restrict__ Win,
                        const float* __restrict__ Wout, const float* __restrict__ Wfin,
                        const float* __restrict__ bout, const float* __restrict__ bfin,
                        const float* __restrict__ blin, const float* __restrict__ Aadj,
                        u16* __restrict__ WinTb, u16* __restrict__ WcombTb,
                        float* __restrict__ bcomb, float* __restrict__ rowsum,
                        unsigned char* __restrict__ A8, u16* __restrict__ Hpb) {
    if (blockIdx.x < 64) {
        const int m0 = blockIdx.x * 128;
        const int t = threadIdx.x;
        const int wave = t >> 6, lane = t & 63;
        const int wm = (wave >> 1) * 64, wn = (wave & 1) * 64;
        const int m16 = lane & 15, kq = lane >> 4;
        f32x4 acc[4][4] = {};

#pragma unroll
        for (int kc = 0; kc < 4; ++kc) {
            bf16x8 af[4], bf[4];
#pragma unroll
            for (int i = 0; i < 4; ++i) {
                const float* ap = &H[(long long)(m0 + wm + i * 16 + m16) * 128 + kc * 32 + kq * 8];
                float4 u0 = *(const float4*)ap;
                float4 u1 = *(const float4*)(ap + 4);
                bf16x8 a;
                a[0] = (short)f2b(u0.x); a[1] = (short)f2b(u0.y);
                a[2] = (short)f2b(u0.z); a[3] = (short)f2b(u0.w);
                a[4] = (short)f2b(u1.x); a[5] = (short)f2b(u1.y);
                a[6] = (short)f2b(u1.z); a[7] = (short)f2b(u1.w);
                af[i] = a;
            }
#pragma unroll
            for (int j = 0; j < 4; ++j) {
                const int col = wn + j * 16 + m16;
                const int k0 = kc * 32 + kq * 8;
                bf16x8 bb;
#pragma unroll
                for (int e = 0; e < 8; ++e)
                    bb[e] = (short)f2b(Wlin[(long long)(k0 + e) * 128 + col]);
                bf[j] = bb;
            }
#pragma unroll
            for (int i = 0; i < 4; ++i)
#pragma unroll
                for (int j = 0; j < 4; ++j)
                    acc[i][j] = MFMAB(af[i], bf[j], acc[i][j]);
        }
#pragma unroll
        for (int i = 0; i < 4; ++i) {
#pragma unroll
            for (int r = 0; r < 4; ++r) {
                long long row = m0 + wm + i * 16 + kq * 4 + r;
#pragma unroll
                for (int j = 0; j < 4; ++j) {
                    int col = wn + j * 16 + m16;
                    Hpb[row * 128 + col] = f2b(acc[i][j][r] + blin[col]);
                }
            }
        }
        return;
    }
    int i = (blockIdx.x - 64) * 256 + threadIdx.x;   // 0..1130495
    if (i >= 81920) {
        int j = i - 81920;                    // 0..1048575: pack 8 elems each
        long long base = (long long)j * 8;
        float4 a0 = *(const float4*)&Aadj[base];
        float4 a1 = *(const float4*)&Aadj[base + 4];
        unsigned long long m = 0;
        m |= (unsigned long long)(a0.x != 0.f) << 0;
        m |= (unsigned long long)(a0.y != 0.f) << 8;
        m |= (unsigned long long)(a0.z != 0.f) << 16;
        m |= (unsigned long long)(a0.w != 0.f) << 24;
        m |= (unsigned long long)(a1.x != 0.f) << 32;
        m |= (unsigned long long)(a1.y != 0.f) << 40;
        m |= (unsigned long long)(a1.z != 0.f) << 48;
        m |= (unsigned long long)(a1.w != 0.f) << 56;
        *(unsigned long long*)&A8[base] = m;
        return;
    }
    if (i < 8192) rowsum[i] = 0.f;
    if (i >= 16384 && i < 65536) {
        int k = i - 16384;                    // Win 128x384 -> WinTb 384x128 bf16
        int r = k / 384, c = k - r * 384;
        WinTb[c * 128 + r] = f2b(Win[k]);
    } else if (i >= 65536) {
        int k = i - 65536;
        int o = k & 127, e = k >> 7;          // o fastest: Wfin coalesced
        float s = 0.f;
        for (int kk = 0; kk < 128; ++kk)
            s = fmaf(Wout[e * 128 + kk], Wfin[kk * 128 + o], s);
        WcombTb[o * 128 + e] = f2b(s);
        if (e == 0) {
            float sb = bfin[o];
            for (int kk = 0; kk < 128; ++kk)
                sb = fmaf(bout[kk], Wfin[kk * 128 + o], sb);
            bcomb[o] = sb;
        }
    }
}

// ---- merged: blk<1024 -> ez = bf16(exp(lrelu(Hpb@Hpb^T)*A8)) + exp-rowsum
//      (128x64 tiles, 2x more blocks than R25 for latency hiding);
//      blk>=1024 -> qkv (all f16: q*0.25 | k | v, 384 halves/row) ----
__global__ __launch_bounds__(256)
void mfma_qkvz(const u16* __restrict__ Hpb, const u16* __restrict__ WinTb,
               const float* __restrict__ bin, f16* __restrict__ Cq,
               const unsigned char* __restrict__ G8, u16* __restrict__ EZ,
               float* __restrict__ rowsum) {
    const int blk = blockIdx.x;
    const int t = threadIdx.x;
    const int wave = t >> 6, lane = t & 63;
    const int wm = (wave >> 1) * 64, wn = (wave & 1) * 64;
    const int m16 = lane & 15, kq = lane >> 4;
    f32x4 acc[4][4] = {};

    if (blk < 1024) {
        const int b = blk >> 7, mt = (blk >> 4) & 7, nt = blk & 15;
        const u16* Ab = Hpb + (long long)b * 1024 * 128;
        const int m0 = mt * 128, n0 = nt * 64;
        const int wn2 = (wave & 1) * 32;     // 2x2 waves over 128x64
#pragma unroll
        for (int kc = 0; kc < 4; ++kc) {
            bf16x8 af[4], bf[2];
#pragma unroll
            for (int i = 0; i < 4; ++i)
                af[i] = *(const bf16x8*)&Ab[(long long)(m0 + wm + i * 16 + m16) * 128 + kc * 32 + kq * 8];
#pragma unroll
            for (int j = 0; j < 2; ++j)
                bf[j] = *(const bf16x8*)&Ab[(long long)(n0 + wn2 + j * 16 + m16) * 128 + kc * 32 + kq * 8];
#pragma unroll
            for (int i = 0; i < 4; ++i)
#pragma unroll
                for (int j = 0; j < 2; ++j)
                    acc[i][j] = MFMAB(af[i], bf[j], acc[i][j]);
        }
        const long long zb = (long long)b * 1024 * 1024;
#pragma unroll
        for (int i = 0; i < 4; ++i) {
#pragma unroll
            for (int r = 0; r < 4; ++r) {
                int row = m0 + wm + i * 16 + kq * 4 + r;
                float es = 0.f;
#pragma unroll
                for (int j = 0; j < 2; ++j) {
                    int col = n0 + wn2 + j * 16 + m16;
                    float v = acc[i][j][r];
                    v = v >= 0.f ? v : 0.2f * v;                  // LeakyReLU(0.2)
                    if (!G8[zb + (long long)row * 1024 + col]) v = 0.f;  // binary gate
                    float ev = __expf(v);                         // m=0: |z| bounded
                    EZ[zb + (long long)row * 1024 + col] = f2b(ev);
                    es += ev;
                }
#pragma unroll
                for (int off = 1; off < 16; off <<= 1) es += __shfl_xor(es, off);
                if (m16 == 0) atomicAdd(&rowsum[b * 1024 + row], es);
            }
        }
    } else {
        const int q = blk - 1024;
        const int mt = q & 63, slab = q >> 6;   // 0=q, 1=k, 2=v
        const int m0 = mt * 128;
        const u16* Bslab = WinTb + (long long)slab * 128 * 128;
#pragma unroll
        for (int kc = 0; kc < 4; ++kc) {
            bf16x8 af[4], bf[4];
#pragma unroll
            for (int i = 0; i < 4; ++i)
                af[i] = *(const bf16x8*)&Hpb[(long long)(m0 + wm + i * 16 + m16) * 128 + kc * 32 + kq * 8];
#pragma unroll
            for (int j = 0; j < 4; ++j)
                bf[j] = *(const bf16x8*)&Bslab[(long long)(wn + j * 16 + m16) * 128 + kc * 32 + kq * 8];
#pragma unroll
            for (int i = 0; i < 4; ++i)
#pragma unroll
                for (int j = 0; j < 4; ++j)
                    acc[i][j] = MFMAB(af[i], bf[j], acc[i][j]);
        }
        const float qscale = (slab == 0) ? 0.25f : 1.f;   // fold 1/sqrt(HD) into q
#pragma unroll
        for (int i = 0; i < 4; ++i) {
#pragma unroll
            for (int r = 0; r < 4; ++r) {
                long long row = m0 + wm + i * 16 + kq * 4 + r;
#pragma unroll
                for (int j = 0; j < 4; ++j) {
                    int col = wn + j * 16 + m16;
                    float v = (acc[i][j][r] + bin[slab * 128 + col]) * qscale;
                    Cq[row * 384 + slab * 128 + col] = (f16)v;
                }
            }
        }
    }
}

// ---- flash (MFMA): block = (b, 64 qrows, 2 heads), full K. 256 thr.
// grid (16,8,4) = 512 blocks -> 2 blk/CU. Byte-identical to R25.
__global__ __launch_bounds__(256)
void flash_mfma(const f16* __restrict__ qkv, const u16* __restrict__ ez,
                const float* __restrict__ rowsum, float* __restrict__ o_) {
    const int n0 = blockIdx.x * 64;
    const int b = blockIdx.y;
    const int h0 = blockIdx.z * 2;       // 2 heads per block
    const int t = threadIdx.x;
    const int w = t >> 6, lane = t & 63;
    const int qr16 = lane & 15, quad = lane >> 4;

    __shared__ u16 Ks[64 * 40];    // [key][dim 0..31 of head pair], stride 40
    __shared__ u16 VTs[32 * 76];   // [dim 0..31][key], stride 76 (bank-safe)
    __shared__ u16 AWs[64 * 72];   // [qrow 0..63][key 0..63] bf16 (ez)

    const int qrow_l = w * 16 + qr16;                 // block-local qrow
    const long long qrow_g = b * 1024 + n0 + qrow_l;  // global qrow
    const float inv0 = 1.f / rowsum[qrow_g];

    f16x4 qf[2];
#pragma unroll
    for (int hh = 0; hh < 2; ++hh)
        qf[hh] = *(const f16x4*)&qkv[qrow_g * 384 + (h0 + hh) * 16 + quad * 4];

    f32x4 accO[2] = {};
    float lacc[2] = {0.f, 0.f};

    for (int st = 0; st < 16; ++st) {
        const int kb = st * 64;
        __syncthreads();
        // stage K (64 keys x 32 dims) b128: key = t>>2, c8 = t&3
        {
            const int key = t >> 2, c8 = t & 3;
            *(uint4*)&Ks[key * 40 + c8 * 8] =
                *(const uint4*)&qkv[((long long)(b * 1024 + kb + key)) * 384 + 128 + h0 * 16 + c8 * 8];
            // stage V transposed: VTs[dim][key]; write bank-step 16 -> <=2-way
            const f16* vsrc = &qkv[((long long)(b * 1024 + kb + key)) * 384 + 256 + h0 * 16 + c8 * 8];
            f16x4 v0 = *(const f16x4*)vsrc;
            f16x4 v1 = *(const f16x4*)(vsrc + 4);
            const int d0 = c8 * 8;
#pragma unroll
            for (int i = 0; i < 4; ++i) {
                VTs[(d0 + i) * 76 + key] = ((const u16*)&v0)[i];
                VTs[(d0 + 4 + i) * 76 + key] = ((const u16*)&v1)[i];
            }
        }
        // stage AW (64 qrows x 64 keys) b128
#pragma unroll
        for (int rr = 0; rr < 2; ++rr) {
            int idx = rr * 256 + t;
            int row = idx >> 3, c16 = idx & 7;
            *(uint4*)&AWs[row * 72 + c16 * 8] =
                *(const uint4*)&ez[((long long)(b * 1024 + n0 + row)) * 1024 + kb + c16 * 8];
        }
        __syncthreads();

#pragma unroll 2
        for (int kt = 0; kt < 4; ++kt) {
            // aw C-init: lane holds (qrow=qr16, keys kt*16+quad*4+r)
            ushort4 ue = *(const ushort4*)&AWs[qrow_l * 72 + kt * 16 + quad * 4];
            f32x4 aw0;
            aw0[0] = b2f(ue.x) * inv0; aw0[1] = b2f(ue.y) * inv0;
            aw0[2] = b2f(ue.z) * inv0; aw0[3] = b2f(ue.w) * inv0;
#pragma unroll
            for (int hh = 0; hh < 2; ++hh) {
                f16x4 kf = *(const f16x4*)&Ks[(kt * 16 + qr16) * 40 + hh * 16 + quad * 4];
                f32x4 s4 = MFMA16(kf, qf[hh], aw0);
                float p0 = __expf(s4[0]), p1 = __expf(s4[1]);
                float p2 = __expf(s4[2]), p3 = __expf(s4[3]);
                lacc[hh] += (p0 + p1) + (p2 + p3);
                f16x4 pf;
                pf[0] = (f16)p0; pf[1] = (f16)p1; pf[2] = (f16)p2; pf[3] = (f16)p3;
                f16x4 vf = *(const f16x4*)&VTs[(hh * 16 + qr16) * 76 + kt * 16 + quad * 4];
                accO[hh] = MFMA16(vf, pf, accO[hh]);
            }
        }
    }
    // finalize: l over quads (lanes sharing qr16), then store o normalized
#pragma unroll
    for (int hh = 0; hh < 2; ++hh) {
        float l = lacc[hh];
        l += __shfl_xor(l, 16);
        l += __shfl_xor(l, 32);
        float inv = 1.f / l;
        float* orow = o_ + qrow_g * 128 + (h0 + hh) * 16 + quad * 4;
#pragma unroll
        for (int r = 0; r < 4; ++r) orow[r] = accO[hh][r] * inv;
    }
}

// -------- out = cast(o_) @ WcombTb^T + bcomb : MFMA, 64-row blocks --------
// R29: 128 blocks (was 64). Each wave: 16 rows x 128 cols, acc[8].
__global__ __launch_bounds__(256)
void mfma_out(const float* __restrict__ A, const u16* __restrict__ Bb,
              const float* __restrict__ bias, float* __restrict__ C) {
    const int m0 = blockIdx.x * 64;
    const int t = threadIdx.x;
    const int wave = t >> 6, lane = t & 63;
    const int wm = wave * 16;            // 4 waves x 16 rows = 64 rows
    const int m16 = lane & 15, kq = lane >> 4;
    f32x4 acc[8] = {};

#pragma unroll
    for (int kc = 0; kc < 4; ++kc) {
        bf16x8 af;
        {
            const float* ap = &A[(long long)(m0 + wm + m16) * 128 + kc * 32 + kq * 8];
            float4 u0 = *(const float4*)ap;
            float4 u1 = *(const float4*)(ap + 4);
            af[0] = (short)f2b(u0.x); af[1] = (short)f2b(u0.y);
            af[2] = (short)f2b(u0.z); af[3] = (short)f2b(u0.w);
            af[4] = (short)f2b(u1.x); af[5] = (short)f2b(u1.y);
            af[6] = (short)f2b(u1.z); af[7] = (short)f2b(u1.w);
        }
        bf16x8 bf[8];
#pragma unroll
        for (int j = 0; j < 8; ++j)
            bf[j] = *(const bf16x8*)&Bb[(long long)(j * 16 + m16) * 128 + kc * 32 + kq * 8];
#pragma unroll
        for (int j = 0; j < 8; ++j)
            acc[j] = MFMAB(af, bf[j], acc[j]);
    }
#pragma unroll
    for (int r = 0; r < 4; ++r) {
        long long row = m0 + wm + kq * 4 + r;
#pragma unroll
        for (int j = 0; j < 8; ++j) {
            int col = j * 16 + m16;
            C[row * 128 + col] = acc[j][r] + bias[col];
        }
    }
}

extern "C" void kernel_launch(void* const* d_in, const int* in_sizes, int n_in,
                              void* d_out, int out_size, void* d_ws, size_t ws_size,
                              hipStream_t stream) {
    (void)in_sizes; (void)n_in; (void)out_size; (void)ws_size;
    const float* H    = (const float*)d_in[0];
    const float* Aadj = (const float*)d_in[1];
    const float* Wlin = (const float*)d_in[2];
    const float* blin = (const float*)d_in[3];
    const float* Win  = (const float*)d_in[4];
    const float* bin  = (const float*)d_in[5];
    const float* Wout = (const float*)d_in[6];
    const float* bout = (const float*)d_in[7];
    const float* Wfin = (const float*)d_in[8];
    const float* bfin = (const float*)d_in[9];
    float* out = (float*)d_out;
    char* ws = (char*)d_ws;

    u16*   WinTb   = (u16*)(ws + 0);          // 96 KB bf16
    u16*   WcombTb = (u16*)(ws + 98304);      // 32 KB bf16
    float* bcomb   = (float*)(ws + 131072);   // 512 B
    float* rowsum  = (float*)(ws + 131584);   // 32 KB
    u16*   Hpb     = (u16*)(ws + 262144);     // 2 MB bf16
    f16*   qkv     = (f16*)(ws + 2359296);    // 6 MB (q f16*0.25 | k f16 | v f16)
    float* o_      = (float*)(ws + 8650752);  // 4 MB
    u16*   ez      = (u16*)(ws + 12845056);   // 16 MB bf16 exp(z)
    unsigned char* A8 = (unsigned char*)(ws + 29622272);  // 8.4 MB u8 gate
    // total ~38 MB

    // merged prep (4416 blocks) + Hp MFMA (64 blocks)
    prep_hp<<<4480, 256, 0, stream>>>(H, Wlin, Win, Wout, Wfin, bout, bfin,
                                      blin, Aadj, WinTb, WcombTb, bcomb,
                                      rowsum, A8, Hpb);
    // merged: ez-gate (1024 blocks, 128x64 tiles) + qkv f16 (192 blocks)
    mfma_qkvz<<<1216, 256, 0, stream>>>(Hpb, WinTb, bin, qkv, A8, ez, rowsum);
    // flash (MFMA, full-K blocks, 2 heads/block, no partials)
    flash_mfma<<<dim3(16, 8, 4), 256, 0, stream>>>(qkv, ez, rowsum, o_);
    // out = cast(o_) @ WcombTb^T + bcomb  (MFMA, 64-row blocks)
    mfma_out<<<128, 256, 0, stream>>>(o_, WcombTb, bcomb, out);
}

// Round 5
// 159.751 us; speedup vs baseline: 2.8859x; 1.0883x over previous
//
#include <hip/hip_runtime.h>
#include <hip/hip_bf16.h>

// GraphAttentionLayer: B=8,N=1024,FIN=E=OUT=128,NH=8,HD=16. f32 in/out.
// R30: R25's proven 4-dispatch structure (R29's re-tilings regressed
// 160.8->173.9; both reverted). Two proven-bit-identical changes applied:
// (1) A8 gate buffer DELETED -- qkvz gates on Aadj!=0 directly (R27/R28 P1
//     body, passed absmax 9.155e-5). prep loses the 32MB+8MB pack section,
//     grid 4480->384. Net -16MB HBM.
// (2) o stored bf16 (R28 P2/P3, passed absmax 9.155e-5): flash finalize
//     f2b's, mfma_out takes bf16x8 A-frags. -4MB traffic, fewer VALU.
// ez section back to 512x(128x128), mfma_out back to 64x(128x128).

using u16 = unsigned short;
typedef short bf16x8 __attribute__((ext_vector_type(8)));
typedef float f32x4 __attribute__((ext_vector_type(4)));
typedef _Float16 f16;
typedef _Float16 f16x4 __attribute__((ext_vector_type(4)));

#define MFMA16(a, b, c) __builtin_amdgcn_mfma_f32_16x16x16f16(a, b, c, 0, 0, 0)
#define MFMAB(a, b, c) __builtin_amdgcn_mfma_f32_16x16x32_bf16(a, b, c, 0, 0, 0)

__device__ __forceinline__ u16 f2b(float f) {
    unsigned u = __float_as_uint(f);
    return (u16)((u + 0x7fffu + ((u >> 16) & 1u)) >> 16);  // RNE
}
__device__ __forceinline__ float b2f(u16 u) {
    return __uint_as_float(((unsigned)u) << 16);
}

// ---- merged prep + Hp-GEMM ----
// blk < 64: Hp = cast(H) @ cast(Wlin)^T + blin  (MFMA, frags packed
//           in-register from f32).
// blk 64..383: rowsum zero + WinTb bf16 + WcombTb bf16 + bcomb.
__global__ void prep_hp(const float* __restrict__ H, const float* __restrict__ Wlin,
                        const float* __restrict__ Win,
                        const float* __restrict__ Wout, const float* __restrict__ Wfin,
                        const float* __restrict__ bout, const float* __restrict__ bfin,
                        const float* __restrict__ blin,
                        u16* __restrict__ WinTb, u16* __restrict__ WcombTb,
                        float* __restrict__ bcomb, float* __restrict__ rowsum,
                        u16* __restrict__ Hpb) {
    if (blockIdx.x < 64) {
        const int m0 = blockIdx.x * 128;
        const int t = threadIdx.x;
        const int wave = t >> 6, lane = t & 63;
        const int wm = (wave >> 1) * 64, wn = (wave & 1) * 64;
        const int m16 = lane & 15, kq = lane >> 4;
        f32x4 acc[4][4] = {};

#pragma unroll
        for (int kc = 0; kc < 4; ++kc) {
            bf16x8 af[4], bf[4];
#pragma unroll
            for (int i = 0; i < 4; ++i) {
                const float* ap = &H[(long long)(m0 + wm + i * 16 + m16) * 128 + kc * 32 + kq * 8];
                float4 u0 = *(const float4*)ap;
                float4 u1 = *(const float4*)(ap + 4);
                bf16x8 a;
                a[0] = (short)f2b(u0.x); a[1] = (short)f2b(u0.y);
                a[2] = (short)f2b(u0.z); a[3] = (short)f2b(u0.w);
                a[4] = (short)f2b(u1.x); a[5] = (short)f2b(u1.y);
                a[6] = (short)f2b(u1.z); a[7] = (short)f2b(u1.w);
                af[i] = a;
            }
#pragma unroll
            for (int j = 0; j < 4; ++j) {
                const int col = wn + j * 16 + m16;
                const int k0 = kc * 32 + kq * 8;
                bf16x8 bb;
#pragma unroll
                for (int e = 0; e < 8; ++e)
                    bb[e] = (short)f2b(Wlin[(long long)(k0 + e) * 128 + col]);
                bf[j] = bb;
            }
#pragma unroll
            for (int i = 0; i < 4; ++i)
#pragma unroll
                for (int j = 0; j < 4; ++j)
                    acc[i][j] = MFMAB(af[i], bf[j], acc[i][j]);
        }
#pragma unroll
        for (int i = 0; i < 4; ++i) {
#pragma unroll
            for (int r = 0; r < 4; ++r) {
                long long row = m0 + wm + i * 16 + kq * 4 + r;
#pragma unroll
                for (int j = 0; j < 4; ++j) {
                    int col = wn + j * 16 + m16;
                    Hpb[row * 128 + col] = f2b(acc[i][j][r] + blin[col]);
                }
            }
        }
        return;
    }
    int i = (blockIdx.x - 64) * 256 + threadIdx.x;   // 0..81919
    if (i < 8192) rowsum[i] = 0.f;
    if (i >= 16384 && i < 65536) {
        int k = i - 16384;                    // Win 128x384 -> WinTb 384x128 bf16
        int r = k / 384, c = k - r * 384;
        WinTb[c * 128 + r] = f2b(Win[k]);
    } else if (i >= 65536) {
        int k = i - 65536;
        int o = k & 127, e = k >> 7;          // o fastest: Wfin coalesced
        float s = 0.f;
        for (int kk = 0; kk < 128; ++kk)
            s = fmaf(Wout[e * 128 + kk], Wfin[kk * 128 + o], s);
        WcombTb[o * 128 + e] = f2b(s);
        if (e == 0) {
            float sb = bfin[o];
            for (int kk = 0; kk < 128; ++kk)
                sb = fmaf(bout[kk], Wfin[kk * 128 + o], sb);
            bcomb[o] = sb;
        }
    }
}

// ---- merged: blk<512 -> ez = bf16(exp(lrelu(Hpb@Hpb^T) gated by Aadj!=0))
//      + exp-rowsum (128x128 tiles, R25 config; gate proven in R27/R28);
//      blk>=512 -> qkv (all f16: q*0.25 | k | v, 384 halves/row) ----
__global__ __launch_bounds__(256)
void mfma_qkvz(const u16* __restrict__ Hpb, const u16* __restrict__ WinTb,
               const float* __restrict__ bin, f16* __restrict__ Cq,
               const float* __restrict__ Aadj, u16* __restrict__ EZ,
               float* __restrict__ rowsum) {
    const int blk = blockIdx.x;
    const int t = threadIdx.x;
    const int wave = t >> 6, lane = t & 63;
    const int wm = (wave >> 1) * 64, wn = (wave & 1) * 64;
    const int m16 = lane & 15, kq = lane >> 4;
    f32x4 acc[4][4] = {};

    if (blk < 512) {
        const int b = blk >> 6, mt = (blk >> 3) & 7, nt = blk & 7;
        const u16* Ab = Hpb + (long long)b * 1024 * 128;
        const int m0 = mt * 128, n0 = nt * 128;
#pragma unroll
        for (int kc = 0; kc < 4; ++kc) {
            bf16x8 af[4], bf[4];
#pragma unroll
            for (int i = 0; i < 4; ++i)
                af[i] = *(const bf16x8*)&Ab[(long long)(m0 + wm + i * 16 + m16) * 128 + kc * 32 + kq * 8];
#pragma unroll
            for (int j = 0; j < 4; ++j)
                bf[j] = *(const bf16x8*)&Ab[(long long)(n0 + wn + j * 16 + m16) * 128 + kc * 32 + kq * 8];
#pragma unroll
            for (int i = 0; i < 4; ++i)
#pragma unroll
                for (int j = 0; j < 4; ++j)
                    acc[i][j] = MFMAB(af[i], bf[j], acc[i][j]);
        }
        const long long zb = (long long)b * 1024 * 1024;
#pragma unroll
        for (int i = 0; i < 4; ++i) {
#pragma unroll
            for (int r = 0; r < 4; ++r) {
                int row = m0 + wm + i * 16 + kq * 4 + r;
                float es = 0.f;
#pragma unroll
                for (int j = 0; j < 4; ++j) {
                    int col = n0 + wn + j * 16 + m16;
                    float v = acc[i][j][r];
                    v = v >= 0.f ? v : 0.2f * v;                    // LeakyReLU(0.2)
                    if (Aadj[zb + (long long)row * 1024 + col] == 0.f) v = 0.f;  // gate
                    float ev = __expf(v);                           // m=0: |z| bounded
                    EZ[zb + (long long)row * 1024 + col] = f2b(ev);
                    es += ev;
                }
#pragma unroll
                for (int off = 1; off < 16; off <<= 1) es += __shfl_xor(es, off);
                if (m16 == 0) atomicAdd(&rowsum[b * 1024 + row], es);
            }
        }
    } else {
        const int q = blk - 512;
        const int mt = q & 63, slab = q >> 6;   // 0=q, 1=k, 2=v
        const int m0 = mt * 128;
        const u16* Bslab = WinTb + (long long)slab * 128 * 128;
#pragma unroll
        for (int kc = 0; kc < 4; ++kc) {
            bf16x8 af[4], bf[4];
#pragma unroll
            for (int i = 0; i < 4; ++i)
                af[i] = *(const bf16x8*)&Hpb[(long long)(m0 + wm + i * 16 + m16) * 128 + kc * 32 + kq * 8];
#pragma unroll
            for (int j = 0; j < 4; ++j)
                bf[j] = *(const bf16x8*)&Bslab[(long long)(wn + j * 16 + m16) * 128 + kc * 32 + kq * 8];
#pragma unroll
            for (int i = 0; i < 4; ++i)
#pragma unroll
                for (int j = 0; j < 4; ++j)
                    acc[i][j] = MFMAB(af[i], bf[j], acc[i][j]);
        }
        const float qscale = (slab == 0) ? 0.25f : 1.f;   // fold 1/sqrt(HD) into q
#pragma unroll
        for (int i = 0; i < 4; ++i) {
#pragma unroll
            for (int r = 0; r < 4; ++r) {
                long long row = m0 + wm + i * 16 + kq * 4 + r;
#pragma unroll
                for (int j = 0; j < 4; ++j) {
                    int col = wn + j * 16 + m16;
                    float v = (acc[i][j][r] + bin[slab * 128 + col]) * qscale;
                    Cq[row * 384 + slab * 128 + col] = (f16)v;
                }
            }
        }
    }
}

// ---- flash (MFMA): block = (b, 64 qrows, 2 heads), full K. 256 thr.
// grid (16,8,4) = 512 blocks -> 2 blk/CU. Body = R25; finalize stores bf16
// (R28 P2, proven absmax-identical).
__global__ __launch_bounds__(256)
void flash_mfma(const f16* __restrict__ qkv, const u16* __restrict__ ez,
                const float* __restrict__ rowsum, u16* __restrict__ ob) {
    const int n0 = blockIdx.x * 64;
    const int b = blockIdx.y;
    const int h0 = blockIdx.z * 2;       // 2 heads per block
    const int t = threadIdx.x;
    const int w = t >> 6, lane = t & 63;
    const int qr16 = lane & 15, quad = lane >> 4;

    __shared__ u16 Ks[64 * 40];    // [key][dim 0..31 of head pair], stride 40
    __shared__ u16 VTs[32 * 76];   // [dim 0..31][key], stride 76 (bank-safe)
    __shared__ u16 AWs[64 * 72];   // [qrow 0..63][key 0..63] bf16 (ez)

    const int qrow_l = w * 16 + qr16;                 // block-local qrow
    const long long qrow_g = b * 1024 + n0 + qrow_l;  // global qrow
    const float inv0 = 1.f / rowsum[qrow_g];

    f16x4 qf[2];
#pragma unroll
    for (int hh = 0; hh < 2; ++hh)
        qf[hh] = *(const f16x4*)&qkv[qrow_g * 384 + (h0 + hh) * 16 + quad * 4];

    f32x4 accO[2] = {};
    float lacc[2] = {0.f, 0.f};

    for (int st = 0; st < 16; ++st) {
        const int kb = st * 64;
        __syncthreads();
        // stage K (64 keys x 32 dims) b128: key = t>>2, c8 = t&3
        {
            const int key = t >> 2, c8 = t & 3;
            *(uint4*)&Ks[key * 40 + c8 * 8] =
                *(const uint4*)&qkv[((long long)(b * 1024 + kb + key)) * 384 + 128 + h0 * 16 + c8 * 8];
            // stage V transposed: VTs[dim][key]; write bank-step 16 -> <=2-way
            const f16* vsrc = &qkv[((long long)(b * 1024 + kb + key)) * 384 + 256 + h0 * 16 + c8 * 8];
            f16x4 v0 = *(const f16x4*)vsrc;
            f16x4 v1 = *(const f16x4*)(vsrc + 4);
            const int d0 = c8 * 8;
#pragma unroll
            for (int i = 0; i < 4; ++i) {
                VTs[(d0 + i) * 76 + key] = ((const u16*)&v0)[i];
                VTs[(d0 + 4 + i) * 76 + key] = ((const u16*)&v1)[i];
            }
        }
        // stage AW (64 qrows x 64 keys) b128
#pragma unroll
        for (int rr = 0; rr < 2; ++rr) {
            int idx = rr * 256 + t;
            int row = idx >> 3, c16 = idx & 7;
            *(uint4*)&AWs[row * 72 + c16 * 8] =
                *(const uint4*)&ez[((long long)(b * 1024 + n0 + row)) * 1024 + kb + c16 * 8];
        }
        __syncthreads();

#pragma unroll 2
        for (int kt = 0; kt < 4; ++kt) {
            // aw C-init: lane holds (qrow=qr16, keys kt*16+quad*4+r)
            ushort4 ue = *(const ushort4*)&AWs[qrow_l * 72 + kt * 16 + quad * 4];
            f32x4 aw0;
            aw0[0] = b2f(ue.x) * inv0; aw0[1] = b2f(ue.y) * inv0;
            aw0[2] = b2f(ue.z) * inv0; aw0[3] = b2f(ue.w) * inv0;
#pragma unroll
            for (int hh = 0; hh < 2; ++hh) {
                f16x4 kf = *(const f16x4*)&Ks[(kt * 16 + qr16) * 40 + hh * 16 + quad * 4];
                f32x4 s4 = MFMA16(kf, qf[hh], aw0);
                float p0 = __expf(s4[0]), p1 = __expf(s4[1]);
                float p2 = __expf(s4[2]), p3 = __expf(s4[3]);
                lacc[hh] += (p0 + p1) + (p2 + p3);
                f16x4 pf;
                pf[0] = (f16)p0; pf[1] = (f16)p1; pf[2] = (f16)p2; pf[3] = (f16)p3;
                f16x4 vf = *(const f16x4*)&VTs[(hh * 16 + qr16) * 76 + kt * 16 + quad * 4];
                accO[hh] = MFMA16(vf, pf, accO[hh]);
            }
        }
    }
    // finalize: l over quads, store o normalized as bf16 (R28 P2, proven)
#pragma unroll
    for (int hh = 0; hh < 2; ++hh) {
        float l = lacc[hh];
        l += __shfl_xor(l, 16);
        l += __shfl_xor(l, 32);
        float inv = 1.f / l;
        ushort4 st4;
        st4.x = f2b(accO[hh][0] * inv);
        st4.y = f2b(accO[hh][1] * inv);
        st4.z = f2b(accO[hh][2] * inv);
        st4.w = f2b(accO[hh][3] * inv);
        *(ushort4*)&ob[qrow_g * 128 + (h0 + hh) * 16 + quad * 4] = st4;
    }
}

// -------- out = ob @ WcombTb^T + bcomb : MFMA, 128-row blocks, bf16 A ----
__global__ __launch_bounds__(256)
void mfma_out(const u16* __restrict__ A, const u16* __restrict__ Bb,
              const float* __restrict__ bias, float* __restrict__ C) {
    const int m0 = blockIdx.x * 128;
    const int t = threadIdx.x;
    const int wave = t >> 6, lane = t & 63;
    const int wm = (wave >> 1) * 64, wn = (wave & 1) * 64;
    const int m16 = lane & 15, kq = lane >> 4;
    f32x4 acc[4][4] = {};

#pragma unroll
    for (int kc = 0; kc < 4; ++kc) {
        bf16x8 af[4], bf[4];
#pragma unroll
        for (int i = 0; i < 4; ++i)
            af[i] = *(const bf16x8*)&A[(long long)(m0 + wm + i * 16 + m16) * 128 + kc * 32 + kq * 8];
#pragma unroll
        for (int j = 0; j < 4; ++j)
            bf[j] = *(const bf16x8*)&Bb[(long long)(wn + j * 16 + m16) * 128 + kc * 32 + kq * 8];
#pragma unroll
        for (int i = 0; i < 4; ++i)
#pragma unroll
            for (int j = 0; j < 4; ++j)
                acc[i][j] = MFMAB(af[i], bf[j], acc[i][j]);
    }
#pragma unroll
    for (int i = 0; i < 4; ++i) {
#pragma unroll
        for (int r = 0; r < 4; ++r) {
            long long row = m0 + wm + i * 16 + kq * 4 + r;
#pragma unroll
            for (int j = 0; j < 4; ++j) {
                int col = wn + j * 16 + m16;
                C[row * 128 + col] = acc[i][j][r] + bias[col];
            }
        }
    }
}

extern "C" void kernel_launch(void* const* d_in, const int* in_sizes, int n_in,
                              void* d_out, int out_size, void* d_ws, size_t ws_size,
                              hipStream_t stream) {
    (void)in_sizes; (void)n_in; (void)out_size; (void)ws_size;
    const float* H    = (const float*)d_in[0];
    const float* Aadj = (const float*)d_in[1];
    const float* Wlin = (const float*)d_in[2];
    const float* blin = (const float*)d_in[3];
    const float* Win  = (const float*)d_in[4];
    const float* bin  = (const float*)d_in[5];
    const float* Wout = (const float*)d_in[6];
    const float* bout = (const float*)d_in[7];
    const float* Wfin = (const float*)d_in[8];
    const float* bfin = (const float*)d_in[9];
    float* out = (float*)d_out;
    char* ws = (char*)d_ws;

    u16*   WinTb   = (u16*)(ws + 0);          // 96 KB bf16
    u16*   WcombTb = (u16*)(ws + 98304);      // 32 KB bf16
    float* bcomb   = (float*)(ws + 131072);   // 512 B
    float* rowsum  = (float*)(ws + 131584);   // 32 KB
    u16*   Hpb     = (u16*)(ws + 262144);     // 2 MB bf16
    f16*   qkv     = (f16*)(ws + 2359296);    // 6 MB (q f16*0.25 | k f16 | v f16)
    u16*   ob      = (u16*)(ws + 8650752);    // 2 MB bf16 normalized o
    u16*   ez      = (u16*)(ws + 12845056);   // 16 MB bf16 exp(z)
    // total ~29 MB

    // prep: Hp MFMA (64 blocks) + weight transposes/combine (320 blocks)
    prep_hp<<<384, 256, 0, stream>>>(H, Wlin, Win, Wout, Wfin, bout, bfin,
                                     blin, WinTb, WcombTb, bcomb, rowsum, Hpb);
    // merged: ez-gate (512 blocks, direct Aadj gate) + qkv f16 (192 blocks)
    mfma_qkvz<<<704, 256, 0, stream>>>(Hpb, WinTb, bin, qkv, Aadj, ez, rowsum);
    // flash (MFMA, full-K blocks, 2 heads/block, bf16 o)
    flash_mfma<<<dim3(16, 8, 4), 256, 0, stream>>>(qkv, ez, rowsum, ob);
    // out = ob @ WcombTb^T + bcomb  (MFMA)
    mfma_out<<<64, 256, 0, stream>>>(ob, WcombTb, bcomb, out);
}